// Round 7
// baseline (277.533 us; speedup 1.0000x reference)
//
#include <hip/hip_runtime.h>

// MeanPooling: segment mean over sorted int32 segment ids.
//   N = 2^25 float32, NUM_SEGMENTS = 100000, index sorted ascending.
// Two-kernel design (r5: fusing search into streaming wave = 207us regression;
// r6: float4 K2 = -11.5us, K2 now ~stream floor).
//   K1 bounds8_kernel: one thread per boundary, 8-ary search: 7 INDEPENDENT
//     probes per round -> dependent rounds 25 -> 9. Round latency ~= one
//     scattered gather (probes issue in parallel before one waitcnt), so the
//     thin-TLP (6 waves/CU) latency-bound kernel should drop ~2x.
//   K2 segsum_kernel: unchanged from r6 (one wave/segment, float4 body,
//     butterfly reduce) -- byte-identical so the A/B delta isolates K1.

#define NSEG 100000

__global__ __launch_bounds__(256) void bounds8_kernel(
    const int* __restrict__ index, int n, int* __restrict__ seg_start) {
    int s = blockIdx.x * blockDim.x + threadIdx.x;
    if (s > NSEG) return;

    // 8-ary lower_bound: first i with index[i] >= s; s==NSEG yields n.
    // Invariant: answer in [lo, hi].
    int lo = 0, hi = n;
    while (hi - lo > 7) {
        int step = (hi - lo) >> 3;            // >= 1
        int v[7];
        #pragma unroll
        for (int k = 0; k < 7; ++k)           // 7 independent gathers
            v[k] = index[lo + (k + 1) * step];
        int cnt = 0;
        #pragma unroll
        for (int k = 0; k < 7; ++k) cnt += (v[k] < s);
        // probes 1..cnt are < s; probe cnt+1 (if any) is >= s.
        int nlo = lo + cnt * step + (cnt > 0 ? 1 : 0);
        int nhi = (cnt < 7) ? lo + (cnt + 1) * step : hi;
        lo = nlo; hi = nhi;
    }
    // Final: range <= 7. lower_bound = lo + #(p in [lo,hi) with index[p] < s).
    int cnt = 0;
    #pragma unroll
    for (int k = 0; k < 7; ++k) {
        int p = lo + k;
        if (p < hi && index[p] < s) ++cnt;
    }
    seg_start[s] = lo + cnt;
}

__global__ __launch_bounds__(256) void segsum_kernel(
    const float* __restrict__ x, const int* __restrict__ seg_start,
    float* __restrict__ out) {
    int wid  = (int)((blockIdx.x * (unsigned)blockDim.x + threadIdx.x) >> 6);
    int lane = threadIdx.x & 63;
    if (wid >= NSEG) return;

    int beg = seg_start[wid];      // L1-broadcast (400KB table, hot)
    int end = seg_start[wid + 1];

    float sum = 0.0f;
    int beg4 = (beg + 3) & ~3;   // first 16B-aligned element index
    int end4 = end & ~3;         // end of aligned body

    if (end4 <= beg4) {
        // Short segment: scalar.
        for (int i = beg + lane; i < end; i += 64) sum += x[i];
    } else {
        // Head: up to 3 scalars.
        if (lane < (beg4 - beg)) sum += x[beg + lane];
        // Body: float4, 16B/lane, 1KiB per wave-instruction.
        for (int i = beg4 + lane * 4; i < end4; i += 64 * 4) {
            float4 v = *reinterpret_cast<const float4*>(x + i);
            sum += v.x + v.y + v.z + v.w;
        }
        // Tail: up to 3 scalars.
        if (lane < (end - end4)) sum += x[end4 + lane];
    }

    // Wave-64 butterfly reduce.
    #pragma unroll
    for (int off = 32; off > 0; off >>= 1) sum += __shfl_down(sum, off, 64);

    if (lane == 0) {
        int cnt = end - beg;
        out[wid] = sum / (float)(cnt > 0 ? cnt : 1);
    }
}

extern "C" void kernel_launch(void* const* d_in, const int* in_sizes, int n_in,
                              void* d_out, int out_size, void* d_ws, size_t ws_size,
                              hipStream_t stream) {
    const float* x   = (const float*)d_in[0];
    const int*   idx = (const int*)d_in[1];
    float*       out = (float*)d_out;
    int n = in_sizes[0];

    int* seg_start = (int*)d_ws;  // NSEG+1 ints = 400004 B of scratch

    {   // K1: boundaries via 8-ary (7-probe) parallel-gather search.
        int threads = 256;
        int blocks = (NSEG + 1 + threads - 1) / threads;
        bounds8_kernel<<<blocks, threads, 0, stream>>>(idx, n, seg_start);
    }
    {   // K2: one wave per segment, float4 streaming sum + mean.
        int threads = 256;                       // 4 waves/block
        int waves_per_block = threads / 64;
        int blocks = (NSEG + waves_per_block - 1) / waves_per_block;
        segsum_kernel<<<blocks, threads, 0, stream>>>(x, seg_start, out);
    }
}